// Round 3
// baseline (1489.941 us; speedup 1.0000x reference)
//
#include <hip/hip_runtime.h>
#include <hip/hip_bf16.h>
#include <cstdint>

#define N_NODES 100000
#define N_EDGES 819200
#define D 512
#define LAYERS 3
#define LN_EPS 1e-5f

// GEMM: 256x256 tiles, 391 row-tiles x 2 col-tiles = 782 blocks (q=97,r=6 vs 8 XCDs)
#define GEMM_GRID 782

typedef __bf16 bf16x8 __attribute__((ext_vector_type(8)));
typedef float floatx4 __attribute__((ext_vector_type(4)));

// ---------- bf16 helpers ----------
__device__ __forceinline__ void bf2x2(uint32_t u, float& lo, float& hi) {
    union { uint32_t i; float f; } a, b;
    a.i = u << 16; b.i = u & 0xFFFF0000u;
    lo = a.f; hi = b.f;
}
__device__ __forceinline__ uint16_t f2bf(float f) {
    union { float f; uint32_t i; } v; v.f = f;
    uint32_t r = v.i + 0x7FFFu + ((v.i >> 16) & 1u);  // RTNE
    return (uint16_t)(r >> 16);
}
__device__ __forceinline__ uint32_t f2bf2(float lo, float hi) {
    return (uint32_t)f2bf(lo) | ((uint32_t)f2bf(hi) << 16);
}

// async global->LDS, 16B per lane (wave writes ldsbase + lane*16)
__device__ __forceinline__ void async16(const uint16_t* g, uint16_t* lds) {
    __builtin_amdgcn_global_load_lds(
        (const __attribute__((address_space(1))) uint32_t*)g,
        (__attribute__((address_space(3))) uint32_t*)lds, 16, 0, 0);
}

#define BARRIER() do { asm volatile("" ::: "memory"); \
                       __builtin_amdgcn_s_barrier();   \
                       asm volatile("" ::: "memory"); } while (0)
#define VMCNT6() asm volatile("s_waitcnt vmcnt(6)" ::: "memory")
#define VMCNT0() asm volatile("s_waitcnt vmcnt(0)" ::: "memory")

// ---------- CSR build ----------
__global__ void k_count(const int* __restrict__ tgt, int* __restrict__ cnt) {
    int e = blockIdx.x * blockDim.x + threadIdx.x;
    if (e < N_EDGES) atomicAdd(&cnt[tgt[e]], 1);
}

__global__ void k_scan(const int* __restrict__ cnt, int* __restrict__ row_start,
                       int* __restrict__ cursor) {
    __shared__ int wsum[16];
    const int t = threadIdx.x;
    const int lane = t & 63, wid = t >> 6;
    int running = 0;
    for (int base = 0; base < N_NODES; base += 1024) {
        int idx = base + t;
        int v = (idx < N_NODES) ? cnt[idx] : 0;
        int x = v;
        #pragma unroll
        for (int off = 1; off < 64; off <<= 1) {
            int n = __shfl_up(x, off, 64);
            if (lane >= off) x += n;
        }
        if (lane == 63) wsum[wid] = x;
        __syncthreads();
        if (wid == 0) {
            int s = (lane < 16) ? wsum[lane] : 0;
            #pragma unroll
            for (int off = 1; off < 16; off <<= 1) {
                int n = __shfl_up(s, off, 64);
                if (lane >= off) s += n;
            }
            if (lane < 16) wsum[lane] = s;
        }
        __syncthreads();
        int waveoff = (wid > 0) ? wsum[wid - 1] : 0;
        int excl = running + x + waveoff - v;
        if (idx < N_NODES) { row_start[idx] = excl; cursor[idx] = excl; }
        int chunk_total = wsum[15];
        __syncthreads();
        running += chunk_total;
    }
    if (t == 0) row_start[N_NODES] = running;
}

__global__ void k_scatter(const int* __restrict__ src, const int* __restrict__ tgt,
                          int* __restrict__ cursor, int* __restrict__ src_sorted) {
    int e = blockIdx.x * blockDim.x + threadIdx.x;
    if (e < N_EDGES) {
        int p = atomicAdd(&cursor[tgt[e]], 1);
        src_sorted[p] = src[e];
    }
}

// ---------- dtype conversion ----------
__global__ void k_f2bf(const float* __restrict__ in, uint16_t* __restrict__ out, int n) {
    int i = (blockIdx.x * blockDim.x + threadIdx.x) * 8;
    if (i < n) {
        float4 a = *(const float4*)(in + i);
        float4 b = *(const float4*)(in + i + 4);
        uint4 o;
        o.x = f2bf2(a.x, a.y); o.y = f2bf2(a.z, a.w);
        o.z = f2bf2(b.x, b.y); o.w = f2bf2(b.z, b.w);
        *(uint4*)(out + i) = o;
    }
}

__global__ void k_wcat(const float* __restrict__ Wl, const float* __restrict__ Wr,
                       uint16_t* __restrict__ wcat) {
    int i = blockIdx.x * blockDim.x + threadIdx.x;
    int k = i & 1023;
    int j = (i >> 10) & 511;
    int l = i >> 19;
    float v = (k < 512) ? Wl[((size_t)l * 512 + j) * 512 + k]
                        : Wr[((size_t)l * 512 + j) * 512 + (k - 512)];
    wcat[i] = f2bf(v);
}

// ---------- mean aggregation: one wave per node, 4-deep gather pipeline ----------
__device__ __forceinline__ void agg_acc(float* acc, uint4 p) {
    float lo, hi;
    bf2x2(p.x, lo, hi); acc[0] += lo; acc[1] += hi;
    bf2x2(p.y, lo, hi); acc[2] += lo; acc[3] += hi;
    bf2x2(p.z, lo, hi); acc[4] += lo; acc[5] += hi;
    bf2x2(p.w, lo, hi); acc[6] += lo; acc[7] += hi;
}

__global__ __launch_bounds__(256)
void k_agg(const uint16_t* __restrict__ x_bf, const int* __restrict__ row_start,
           const int* __restrict__ src_sorted, uint16_t* __restrict__ agg_bf) {
    const int wid = threadIdx.x >> 6, lane = threadIdx.x & 63;
    const int node = blockIdx.x * 4 + wid;
    if (node >= N_NODES) return;
    const int s0 = row_start[node], s1 = row_start[node + 1];
    const int col = lane * 8;
    float acc[8] = {0.f, 0.f, 0.f, 0.f, 0.f, 0.f, 0.f, 0.f};
    int e = s0;
    for (; e + 4 <= s1; e += 4) {
        int i0 = src_sorted[e], i1 = src_sorted[e + 1];
        int i2 = src_sorted[e + 2], i3 = src_sorted[e + 3];
        uint4 p0 = *(const uint4*)(x_bf + (size_t)i0 * D + col);
        uint4 p1 = *(const uint4*)(x_bf + (size_t)i1 * D + col);
        uint4 p2 = *(const uint4*)(x_bf + (size_t)i2 * D + col);
        uint4 p3 = *(const uint4*)(x_bf + (size_t)i3 * D + col);
        agg_acc(acc, p0); agg_acc(acc, p1); agg_acc(acc, p2); agg_acc(acc, p3);
    }
    if (e + 2 <= s1) {
        int i0 = src_sorted[e], i1 = src_sorted[e + 1];
        uint4 p0 = *(const uint4*)(x_bf + (size_t)i0 * D + col);
        uint4 p1 = *(const uint4*)(x_bf + (size_t)i1 * D + col);
        agg_acc(acc, p0); agg_acc(acc, p1);
        e += 2;
    }
    if (e < s1) {
        int i0 = src_sorted[e];
        uint4 p0 = *(const uint4*)(x_bf + (size_t)i0 * D + col);
        agg_acc(acc, p0);
    }
    const float inv = (s1 > s0) ? 1.0f / (float)(s1 - s0) : 0.0f;
    uint4 o;
    o.x = f2bf2(acc[0] * inv, acc[1] * inv);
    o.y = f2bf2(acc[2] * inv, acc[3] * inv);
    o.z = f2bf2(acc[4] * inv, acc[5] * inv);
    o.w = f2bf2(acc[6] * inv, acc[7] * inv);
    *(uint4*)(agg_bf + (size_t)node * D + col) = o;
}

// ---------- GEMM: h = [agg|x] @ Wcat^T ----------
// 256x256 tile, BK=64, 512 threads (8 waves, 2Mx4N), 128KB LDS double-buffer.
// 8-phase schedule (T3+T4): counted vmcnt(6) at phases 4/8 only, raw s_barrier
// (no vmcnt drain), setprio around MFMA clusters (T5), XOR-swizzled LDS via
// pre-swizzled global source + linear global_load_lds dest (T2, rule #21).
//
// LDS layout per tile: [256 rows][64 k] bf16, row = 128B. Slot s (16B) of row r
// holds global k-octet s ^ (r&7)  -> fragment read (lane qm of octet q, row r)
// reads slot q^(r&7): spreads across all 8 slots -> residual 2-way (free, m136).
// Stage: wave w, load j covers rows h*128+j*64+w*8 .. +7 linearly; lane l fetches
// global octet (l&7)^((l>>3)&7) so the linear LDS write realizes the swizzle.
//
// Phase schedule per iteration (tiles te=2i -> buf0, to=2i+1 -> buf1):
//  P1: rd A(M0-3),B(N0-1) buf0 | stage buf1 A-hi(to)      | Q0: acc[0-3][0-1]
//  P2: rd B(N2-3) buf0         |                          | Q1: acc[0-3][2-3]
//  P3: rd A(M4-7) buf0         | stage buf0 B-lo,B-hi(te+2)| Q2: acc[4-7][0-1]
//  P4:                         | stage buf0 A-lo(te+2); VMCNT6 | Q3: acc[4-7][2-3]
//  P5-P8: mirror on buf1 (to), staging buf0 A-hi(te+2), buf1 B/A-lo(to+2)
// vmcnt ledger (per wave): steady in-flight at P4 = 6(to partial)+2(P1)+4(P3)+2(P4)
// = 14; vmcnt(6) drains oldest 8 = tile `to` complete. P8 symmetric (drains te+2).
// Every stage overwrites LDS whose last ds_read was lgkm-consumed >=1 barrier ago.
// Last iter stages clamp to tile 15 (rewrites identical data -> benign).
//
// __launch_bounds__(512, 1): LDS (128KB) already caps at 1 block/CU; requesting
// 2 waves/EU would cap VGPRs at 256 vs ~222 needed -> spill risk inside the
// counted-vmcnt loop (scratch ops corrupt the hand-counted ledger). Keep 1.
__global__ __launch_bounds__(512, 1)
void k_gemm(const uint16_t* __restrict__ A0,   // agg_bf [N][512]  (k<512, tiles 0-7)
            const uint16_t* __restrict__ A1,   // x_bf   [N][512]  (k>=512, tiles 8-15)
            const uint16_t* __restrict__ W,    // wcat layer [512][1024]
            uint16_t* __restrict__ Hout)       // h_bf [N][512]
{
    __shared__ uint16_t Ash0[256 * 64];   // 32KB each, 128KB total
    __shared__ uint16_t Ash1[256 * 64];
    __shared__ uint16_t Bsh0[256 * 64];
    __shared__ uint16_t Bsh1[256 * 64];

    const int tid = threadIdx.x;
    const int l = tid & 63, w = tid >> 6;
    const int wm = w >> 2, wn = w & 3;            // 2x4 wave grid
    const int wmA = wm * 128, wnB = wn * 64;      // per-wave output: 128 x 64
    const int mrow = l & 15, qbase = l >> 4, sw7 = l & 7;

    // bijective XCD swizzle for 782 blocks over 8 XCDs (q=97, r=6) [m204]
    const int bid = blockIdx.x;
    const int xcd = bid & 7, pos = bid >> 3;
    const int wk = (xcd < 6 ? xcd * 98 : 588 + (xcd - 6) * 97) + pos;
    const int rb = wk >> 1, cb = wk & 1;
    const int row0 = rb * 256, col0 = cb * 256;

    // staging geometry: per load-instr, wave w covers 8 rows; lane l -> row +(l>>3),
    // fetching swizzled global octet o16 so linear LDS dest realizes the swizzle
    const int ra = w * 8 + (l >> 3);              // 0..63
    const int o16 = (l & 7) ^ ((l >> 3) & 7);
    uint32_t offA[2][2], offB[2][2];              // byte offsets (fit u32)
    #pragma unroll
    for (int h = 0; h < 2; h++)
        #pragma unroll
        for (int j = 0; j < 2; j++) {
            int rr = h * 128 + j * 64 + ra;
            int gra = row0 + rr; if (gra > N_NODES - 1) gra = N_NODES - 1;
            offA[h][j] = (uint32_t)gra * 1024u + (uint32_t)o16 * 16u;
            offB[h][j] = (uint32_t)(col0 + rr) * 2048u + (uint32_t)o16 * 16u;
        }

    auto stA = [&](uint16_t* buf, int h, int t_) {   // one A half-tile: 2 loads
        int ts = t_ < 15 ? t_ : 15;
        const char* base; uint32_t koff;
        if (ts < 8) { base = (const char*)A0; koff = (uint32_t)ts * 128u; }
        else        { base = (const char*)A1; koff = (uint32_t)(ts - 8) * 128u; }
        async16((const uint16_t*)(base + offA[h][0] + koff), buf + (h * 128 + w * 8) * 64);
        async16((const uint16_t*)(base + offA[h][1] + koff), buf + (h * 128 + 64 + w * 8) * 64);
    };
    auto stB = [&](uint16_t* buf, int h, int t_) {   // one B half-tile: 2 loads
        int ts = t_ < 15 ? t_ : 15;
        uint32_t koff = (uint32_t)ts * 128u;
        async16((const uint16_t*)((const char*)W + offB[h][0] + koff), buf + (h * 128 + w * 8) * 64);
        async16((const uint16_t*)((const char*)W + offB[h][1] + koff), buf + (h * 128 + 64 + w * 8) * 64);
    };

    floatx4 acc[8][4] = {};
    bf16x8 af[4][2], bA[2][2], bB[2][2];

    auto rdA4 = [&](bf16x8 a_[4][2], const uint16_t* buf, int rbase) {
        #pragma unroll
        for (int mr = 0; mr < 4; mr++) {
            int r = wmA + rbase + mr * 16 + mrow;
            #pragma unroll
            for (int kh = 0; kh < 2; kh++) {
                int slot = (kh * 4 + qbase) ^ sw7;   // r&7 == l&7 here
                a_[mr][kh] = *(const bf16x8*)(buf + r * 64 + slot * 8);
            }
        }
    };
    auto rdB2 = [&](bf16x8 b_[2][2], const uint16_t* buf, int nbase) {
        #pragma unroll
        for (int nr = 0; nr < 2; nr++) {
            int r = wnB + (nbase + nr) * 16 + mrow;
            #pragma unroll
            for (int kh = 0; kh < 2; kh++) {
                int slot = (kh * 4 + qbase) ^ sw7;
                b_[nr][kh] = *(const bf16x8*)(buf + r * 64 + slot * 8);
            }
        }
    };
    auto quad = [&](const bf16x8 a_[4][2], const bf16x8 b_[2][2], int mb, int nb) {
        __builtin_amdgcn_s_setprio(1);
        #pragma unroll
        for (int mr = 0; mr < 4; mr++)
            #pragma unroll
            for (int nr = 0; nr < 2; nr++)
                #pragma unroll
                for (int kh = 0; kh < 2; kh++)
                    acc[mb + mr][nb + nr] = __builtin_amdgcn_mfma_f32_16x16x32_bf16(
                        a_[mr][kh], b_[nr][kh], acc[mb + mr][nb + nr], 0, 0, 0);
        __builtin_amdgcn_s_setprio(0);
    };

    // prologue: tile0 fully (8 loads) + tile1 B-lo,B-hi,A-lo (6 loads)
    stB(Bsh0, 0, 0); stB(Bsh0, 1, 0); stA(Ash0, 0, 0); stA(Ash0, 1, 0);
    stB(Bsh1, 0, 1); stB(Bsh1, 1, 1); stA(Ash1, 0, 1);
    VMCNT6();        // drain tile0 (oldest 8), keep tile1's 6 in flight
    BARRIER();

    #pragma unroll 1
    for (int i = 0; i < 8; i++) {
        const int te = 2 * i, to = 2 * i + 1;
        // P1
        rdA4(af, Ash0, 0); rdB2(bA, Bsh0, 0);
        stA(Ash1, 1, to);                       // finish tile `to` (A-hi)
        BARRIER(); quad(af, bA, 0, 0); BARRIER();
        // P2
        rdB2(bB, Bsh0, 2);
        BARRIER(); quad(af, bB, 0, 2); BARRIER();
        // P3
        rdA4(af, Ash0, 64);
        stB(Bsh0, 0, te + 2); stB(Bsh0, 1, te + 2);
        BARRIER(); quad(af, bA, 4, 0); BARRIER();
        // P4
        stA(Ash0, 0, te + 2);
        VMCNT6();                               // drains tile `to` completely
        BARRIER(); quad(af, bB, 4, 2); BARRIER();
        // P5
        rdA4(af, Ash1, 0); rdB2(bA, Bsh1, 0);
        stA(Ash0, 1, te + 2);
        BARRIER(); quad(af, bA, 0, 0); BARRIER();
        // P6
        rdB2(bB, Bsh1, 2);
        BARRIER(); quad(af, bB, 0, 2); BARRIER();
        // P7
        rdA4(af, Ash1, 64);
        stB(Bsh1, 0, to + 2); stB(Bsh1, 1, to + 2);
        BARRIER(); quad(af, bA, 4, 0); BARRIER();
        // P8
        stA(Ash1, 0, to + 2);
        VMCNT6();                               // drains tile te+2 completely
        BARRIER(); quad(af, bB, 4, 2); BARRIER();
    }
    VMCNT0();   // drain leftover (clamped) prefetches before exit

    // epilogue: C/D layout col=lane&15, row=(lane>>4)*4+reg  [m89-verified]
    #pragma unroll
    for (int mr = 0; mr < 8; mr++) {
        #pragma unroll
        for (int rr = 0; rr < 4; rr++) {
            int grow = row0 + wmA + mr * 16 + qbase * 4 + rr;
            if (grow < N_NODES) {
                #pragma unroll
                for (int nr = 0; nr < 4; nr++) {
                    int gcol = col0 + wnB + nr * 16 + mrow;
                    Hout[(size_t)grow * 512 + gcol] = f2bf(acc[mr][nr][rr]);
                }
            }
        }
    }
}

// ---------- fused bias + LayerNorm + ReLU + residual: one wave per row ----------
__global__ __launch_bounds__(256)
void k_ln(const uint16_t* __restrict__ H, const float* __restrict__ bias,
          const float* __restrict__ gam, const float* __restrict__ bet,
          uint16_t* __restrict__ xbf,     // in: residual source; out (if !last): next x
          float* __restrict__ out32, int last) {
    const int wid = threadIdx.x >> 6, lane = threadIdx.x & 63;
    const int node = blockIdx.x * 4 + wid;
    if (node >= N_NODES) return;
    const int col = lane * 8;
    const size_t off = (size_t)node * D + col;

    uint4 hp = *(const uint4*)(H + off);
    float v[8];
    bf2x2(hp.x, v[0], v[1]); bf2x2(hp.y, v[2], v[3]);
    bf2x2(hp.z, v[4], v[5]); bf2x2(hp.w, v[6], v[7]);
    float4 b0 = *(const float4*)(bias + col), b1 = *(const float4*)(bias + col + 4);
    v[0] += b0.x; v[1] += b0.y; v[2] += b0.z; v[3] += b0.w;
    v[4] += b1.x; v[5] += b1.y; v[6] += b1.z; v[7] += b1.w;

    float s = 0.f;
    #pragma unroll
    for (int i = 0; i < 8; i++) s += v[i];
    #pragma unroll
    for (int o = 32; o >= 1; o >>= 1) s += __shfl_xor(s, o, 64);
    float mu = s * (1.0f / D);
    float vs = 0.f;
    #pragma unroll
    for (int i = 0; i < 8; i++) { float d = v[i] - mu; vs += d * d; }
    #pragma unroll
    for (int o = 32; o >= 1; o >>= 1) vs += __shfl_xor(vs, o, 64);
    float rstd = rsqrtf(vs * (1.0f / D) + LN_EPS);

    float4 g0 = *(const float4*)(gam + col), g1 = *(const float4*)(gam + col + 4);
    float4 e0 = *(const float4*)(bet + col), e1 = *(const float4*)(bet + col + 4);
    float gg[8] = {g0.x, g0.y, g0.z, g0.w, g1.x, g1.y, g1.z, g1.w};
    float ee[8] = {e0.x, e0.y, e0.z, e0.w, e1.x, e1.y, e1.z, e1.w};

    uint4 xp = *(const uint4*)(xbf + off);
    float xi[8];
    bf2x2(xp.x, xi[0], xi[1]); bf2x2(xp.y, xi[2], xi[3]);
    bf2x2(xp.z, xi[4], xi[5]); bf2x2(xp.w, xi[6], xi[7]);

    float o_[8];
    #pragma unroll
    for (int i = 0; i < 8; i++) {
        float h = (v[i] - mu) * rstd * gg[i] + ee[i];
        o_[i] = fmaxf(h, 0.f) + xi[i];
    }
    if (last) {
        float4 f0 = {o_[0], o_[1], o_[2], o_[3]};
        float4 f1 = {o_[4], o_[5], o_[6], o_[7]};
        *(float4*)(out32 + off) = f0;
        *(float4*)(out32 + off + 4) = f1;
    } else {
        uint4 o;
        o.x = f2bf2(o_[0], o_[1]); o.y = f2bf2(o_[2], o_[3]);
        o.z = f2bf2(o_[4], o_[5]); o.w = f2bf2(o_[6], o_[7]);
        *(uint4*)(xbf + off) = o;
    }
}

extern "C" void kernel_launch(void* const* d_in, const int* in_sizes, int n_in,
                              void* d_out, int out_size, void* d_ws, size_t ws_size,
                              hipStream_t stream) {
    const float* x   = (const float*)d_in[0];
    const int*   ei  = (const int*)d_in[1];          // [2][N_EDGES]: src row0, tgt row1
    const float* Wl  = (const float*)d_in[2];
    const float* Wr  = (const float*)d_in[3];
    const float* b   = (const float*)d_in[4];
    const float* g   = (const float*)d_in[5];
    const float* be  = (const float*)d_in[6];
    float* out = (float*)d_out;
    const int* src = ei;
    const int* tgt = ei + N_EDGES;

    size_t off = 0;
    auto alloc = [&](size_t bytes) -> void* {
        void* p = (char*)d_ws + off;
        off += (bytes + 255) & ~(size_t)255;
        return p;
    };
    int* cnt        = (int*)alloc((size_t)N_NODES * 4);
    int* row_start  = (int*)alloc((size_t)(N_NODES + 1) * 4);
    int* cursor     = (int*)alloc((size_t)N_NODES * 4);
    int* src_sorted = (int*)alloc((size_t)N_EDGES * 4);
    uint16_t* wcat  = (uint16_t*)alloc((size_t)LAYERS * 512 * 1024 * 2);
    uint16_t* x_bf  = (uint16_t*)alloc((size_t)N_NODES * D * 2);
    uint16_t* agg_bf= (uint16_t*)alloc((size_t)N_NODES * D * 2);
    uint16_t* h_bf  = (uint16_t*)alloc((size_t)N_NODES * D * 2);

    (void)hipMemsetAsync(cnt, 0, (size_t)N_NODES * 4, stream);
    k_count<<<N_EDGES / 256, 256, 0, stream>>>(tgt, cnt);
    k_scan<<<1, 1024, 0, stream>>>(cnt, row_start, cursor);
    k_scatter<<<N_EDGES / 256, 256, 0, stream>>>(src, tgt, cursor, src_sorted);
    k_f2bf<<<(N_NODES * D / 8) / 256, 256, 0, stream>>>(x, x_bf, N_NODES * D);
    k_wcat<<<(LAYERS * 512 * 1024) / 256, 256, 0, stream>>>(Wl, Wr, wcat);

    for (int l = 0; l < LAYERS; l++) {
        k_agg<<<N_NODES / 4, 256, 0, stream>>>(x_bf, row_start, src_sorted, agg_bf);
        k_gemm<<<GEMM_GRID, 512, 0, stream>>>(agg_bf, x_bf,
                                              wcat + (size_t)l * 512 * 1024, h_bf);
        k_ln<<<N_NODES / 4, 256, 0, stream>>>(h_bf, b + l * D, g + l * D, be + l * D,
                                              x_bf, out, l == 2 ? 1 : 0);
    }
}